// Round 15
// baseline (3162.728 us; speedup 1.0000x reference)
//
#include <hip/hip_runtime.h>
#include <math.h>

// Round 15 = Round 14 (PASSED, 2.74 ms) + kY occupancy fix:
//  kY: 512-thread blocks, 2 blocks per (n,h,fw) row (grid 4096, pair-adjacent
//  for L2 reuse of the x tile). 8 wave-groups x 32 channels each -> one pass
//  per wave, 16 waves/CU instead of ~6. Arithmetic chain untouched (bit-exact).
//  kCen/kNC/kSim/kAgg/kOut: verbatim from round 14.
//
// ORDERING-PATH INVARIANT: y = seq-c mul+add + f32 bias; center = tree8 over
// b, left-fold over a, /64; norms = pw32; nx/nc = f32 div; sim = dot32_sse
// reduce (s0+s1)+(s2+s3); argmax = FIRST max over RAW f32 sims; mv = f32
// sigmoid chain (CR exp via f64).
//
// Geometry: n=8, c=256, h=128, w=128; FC=8, FH=FW=2, CS=8
// sc=64, scv=32, sh=sw=64, m=256, l=4096, s=64
//
// Workspace (285 MiB): Y[64M] CB[1M] NCB[512K] MAXV[1M] MAXI[1M] AGG[512K] floats

__device__ __forceinline__ float tree8(const float* a) {
    float t01 = __fadd_rn(a[0], a[1]);
    float t23 = __fadd_rn(a[2], a[3]);
    float t45 = __fadd_rn(a[4], a[5]);
    float t67 = __fadd_rn(a[6], a[7]);
    return __fadd_rn(__fadd_rn(t01, t23), __fadd_rn(t45, t67));
}
__device__ __forceinline__ float pw32(const float* a) {
    float r[8];
    #pragma unroll
    for (int j = 0; j < 8; ++j) r[j] = a[j];
    #pragma unroll
    for (int i = 8; i < 32; i += 8) {
        #pragma unroll
        for (int j = 0; j < 8; ++j) r[j] = __fadd_rn(r[j], a[i + j]);
    }
    float t01 = __fadd_rn(r[0], r[1]);
    float t23 = __fadd_rn(r[2], r[3]);
    float t45 = __fadd_rn(r[4], r[5]);
    float t67 = __fadd_rn(r[6], r[7]);
    return __fadd_rn(__fadd_rn(t01, t23), __fadd_rn(t45, t67));
}
__device__ __forceinline__ float dot32_sse(const float* a, const float* b) {
    float s0 = 0.f, s1 = 0.f, s2 = 0.f, s3 = 0.f;
    #pragma unroll
    for (int k = 0; k < 32; k += 4) {
        s0 = __fadd_rn(s0, __fmul_rn(a[k + 0], b[k + 0]));
        s1 = __fadd_rn(s1, __fmul_rn(a[k + 1], b[k + 1]));
        s2 = __fadd_rn(s2, __fmul_rn(a[k + 2], b[k + 2]));
        s3 = __fadd_rn(s3, __fmul_rn(a[k + 3], b[k + 3]));
    }
    return __fadd_rn(__fadd_rn(s0, s1), __fadd_rn(s2, s3));
}

// ---- kY v2: 512 thr; block pair covers one (n,h,fw) row; 8 groups x 32 ch ----
__global__ __launch_bounds__(512, 4) void kY(
    const float* __restrict__ x, const float* __restrict__ Wp,
    const float* __restrict__ bp, float* __restrict__ Y)
{
    __shared__ float xs[256 * 64];          // [c][px] 64 KiB
    int b = blockIdx.x;                     // 4096 = (n*256 + h*2 + fw)*2 + half
    int half = b & 1;
    int row = b >> 1;
    int n = row >> 8; int rem = row & 255;
    int h = rem >> 1, fw = rem & 1;
    int fh = h >> 6, sh = h & 63;
    int t = threadIdx.x;
    {
        float4* xs4 = (float4*)xs;
        const float4* xsrc = (const float4*)x;
        #pragma unroll
        for (int i = 0; i < 8; ++i) {
            int id = i * 512 + t;           // 4096 float4s
            int c = id >> 4, p4 = id & 15;
            size_t base = ((size_t)(n * 256 + c) * 128 + h) * 128 + fw * 64;
            xs4[id] = xsrc[base / 4 + p4];
        }
    }
    __syncthreads();
    int px = t & 63;
    int grp = __builtin_amdgcn_readfirstlane(t >> 6);   // 0..7, wave-uniform
    int d0 = half * 256 + grp * 32;
    float acc[32];
    #pragma unroll
    for (int j = 0; j < 32; ++j) acc[j] = 0.f;
    const float* wbase = Wp + (size_t)d0 * 256;
    for (int c = 0; c < 256; ++c) {         // EXACT: sequential c, mul+add
        float xv = xs[c * 64 + px];
        #pragma unroll
        for (int j = 0; j < 32; ++j)
            acc[j] = __fadd_rn(acc[j], __fmul_rn(wbase[j * 256 + c], xv));
    }
    #pragma unroll
    for (int j = 0; j < 32; ++j) {
        int d = d0 + j;
        float yv = __fadd_rn(acc[j], bp[d]);            // EXACT: f32 bias add
        int fc = d >> 6, sc = d & 63;
        int m = ((n * 8 + fc) * 2 + fh) * 2 + fw;
        Y[((size_t)(m * 64 + sc)) * 4096 + sh * 64 + px] = yv;
    }
}

// ---- kCen: verbatim ----
__global__ __launch_bounds__(256) void kCen(
    const float* __restrict__ Y, float* __restrict__ CB)
{
    int m = blockIdx.x;
    int t = threadIdx.x;
    for (int i = t; i < 4096; i += 256) {
        int s = i >> 6, ch = i & 63;
        int ci = s >> 3, cj = s & 7;
        const float* yb = Y + ((size_t)(m * 64 + ch)) * 4096;
        float total = 0.f;
        #pragma unroll
        for (int a = 0; a < 8; ++a) {
            float v[8];
            #pragma unroll
            for (int b2 = 0; b2 < 8; ++b2)
                v[b2] = yb[(ci * 8 + a) * 64 + cj * 8 + b2];
            float tr = tree8(v);
            total = (a == 0) ? tr : __fadd_rn(total, tr);
        }
        CB[((size_t)m * 64 + s) * 64 + ch] = __fdiv_rn(total, 64.0f);
    }
}

// ---- kNC: verbatim (bit-frozen) ----
__global__ __launch_bounds__(64) void kNC(
    const float* __restrict__ CB, float* __restrict__ NCB)
{
    int m = blockIdx.x, s = threadIdx.x;
    const float* row = CB + ((size_t)m * 64 + s) * 64;
    float sq[32];
    #pragma unroll
    for (int k = 0; k < 32; ++k) sq[k] = __fmul_rn(row[k], row[k]);
    float n2 = pw32(sq);
    float nr = __fsqrt_rn(n2);
    float mx = fmaxf(nr, 1e-12f);
    #pragma unroll
    for (int k = 0; k < 32; ++k)
        NCB[((size_t)m * 64 + s) * 32 + k] = __fdiv_rn(row[k], mx);
}

// ---- kSim: verbatim (bit-frozen) ----
__global__ __launch_bounds__(256) void kSim(
    const float* __restrict__ Y, const float* __restrict__ NCB,
    const float* __restrict__ alphap, const float* __restrict__ betap,
    float* __restrict__ MAXV, int* __restrict__ MAXI)
{
    __shared__ float ncl[64 * 32];    // 8 KiB
    int b = blockIdx.x;               // 1024 = m*4 + q
    int m = b >> 2, q = b & 3;
    int t = threadIdx.x;
    for (int i = t; i < 2048; i += 256) ncl[i] = NCB[(size_t)m * 2048 + i];
    __syncthreads();

    float al = alphap[0], be = betap[0];
    for (int it = 0; it < 4; ++it) {
        int l = q * 1024 + it * 256 + t;
        float xp[32];
        #pragma unroll
        for (int k = 0; k < 32; ++k)
            xp[k] = Y[((size_t)(m * 64 + k)) * 4096 + l];   // coalesced
        float sq[32];
        #pragma unroll
        for (int k = 0; k < 32; ++k) sq[k] = __fmul_rn(xp[k], xp[k]);
        float nr = __fsqrt_rn(pw32(sq));
        float mx = fmaxf(nr, 1e-12f);
        float nx[32];
        #pragma unroll
        for (int k = 0; k < 32; ++k) nx[k] = __fdiv_rn(xp[k], mx);

        float best = -3.0e38f; int bi = 0;
        for (int s = 0; s < 64; ++s) {
            float dot = dot32_sse(nx, ncl + s * 32);
            if (dot > best) { best = dot; bi = s; }
        }
        float z = __fadd_rn(__fmul_rn(al, best), be);
        float e = (float)exp(-(double)z);
        float den = __fadd_rn(1.0f, e);
        float sv = __fdiv_rn(1.0f, den);
        MAXV[(size_t)m * 4096 + l] = sv;
        MAXI[(size_t)m * 4096 + l] = bi;
    }
}

// ---- kAgg: verbatim ----
__global__ __launch_bounds__(256) void kAgg(
    const float* __restrict__ Y, const float* __restrict__ CB,
    const float* __restrict__ MAXV, const int* __restrict__ MAXI,
    float* __restrict__ AGG)
{
    __shared__ float ag[64 * 33];     // [s][value32 + weight] 8.25 KiB
    int m = blockIdx.x;
    int t = threadIdx.x;
    for (int i = t; i < 64 * 33; i += 256) {
        int s = i / 33, v = i - s * 33;
        ag[i] = (v < 32) ? CB[((size_t)m * 64 + s) * 64 + 32 + v] : 1.0f;
    }
    __syncthreads();
    for (int it = 0; it < 16; ++it) {
        int l = it * 256 + t;
        float mv = MAXV[(size_t)m * 4096 + l];
        int s = MAXI[(size_t)m * 4096 + l];
        float* row = ag + s * 33;     // 33 ≡ 1 (mod 32): distinct s -> distinct bank
        #pragma unroll
        for (int k = 0; k < 32; ++k) {
            float yv = Y[((size_t)(m * 64 + 32 + k)) * 4096 + l];  // coalesced
            atomicAdd(&row[k], mv * yv);
        }
        atomicAdd(&row[32], mv);
    }
    __syncthreads();
    for (int i = t; i < 2048; i += 256) {
        int s = i >> 5, v = i & 31;
        AGG[(size_t)m * 2048 + i] = __fdiv_rn(ag[s * 33 + v], ag[s * 33 + 32]);
    }
}

// ---- kOut: verbatim ----
__global__ __launch_bounds__(256) void kOut(
    const float* __restrict__ AGG, const float* __restrict__ MAXV,
    const int* __restrict__ MAXI, const float* __restrict__ Wm,
    const float* __restrict__ bm, float* __restrict__ out)
{
    __shared__ float dsp[256 * 64];   // [c2 = fc*32+v][px]  64 KiB
    int b = blockIdx.x;               // 2048 = n*256 + h*2 + fw
    int n = b >> 8; int rem = b & 255;
    int h = rem >> 1, fw = rem & 1;
    int fh = h >> 6, sh = h & 63;
    int t = threadIdx.x;
    for (int rep = 0; rep < 2; ++rep) {
        int pair = rep * 256 + t;     // fc(8) * px(64)
        int fc = pair >> 6, px = pair & 63;
        int m = ((n * 8 + fc) * 2 + fh) * 2 + fw;
        int l = sh * 64 + px;
        float mv = MAXV[(size_t)m * 4096 + l];
        int s = MAXI[(size_t)m * 4096 + l];
        const float* ar = AGG + ((size_t)m * 64 + s) * 32;
        #pragma unroll
        for (int v = 0; v < 32; ++v)
            dsp[(fc * 32 + v) * 64 + px] = __fmul_rn(mv, ar[v]);
    }
    __syncthreads();
    int d = t;
    float a[64];
    #pragma unroll
    for (int p = 0; p < 64; ++p) a[p] = 0.f;
    const float* wr = Wm + (size_t)d * 256;
    for (int c = 0; c < 256; ++c) {
        float wv = wr[c];
        const float* row = dsp + c * 64;
        #pragma unroll
        for (int p = 0; p < 64; ++p)
            a[p] = __fadd_rn(a[p], __fmul_rn(wv, row[p]));
    }
    float bb = bm[d];
    float* orow = out + ((size_t)(n * 256 + d) * 128 + h) * 128 + fw * 64;
    for (int p = 0; p < 64; ++p)
        orow[p] = __fadd_rn(a[p], bb);
}

extern "C" void kernel_launch(void* const* d_in, const int* in_sizes, int n_in,
                              void* d_out, int out_size, void* d_ws, size_t ws_size,
                              hipStream_t stream)
{
    const float* x     = (const float*)d_in[0];
    const float* Wp    = (const float*)d_in[1];
    const float* bp    = (const float*)d_in[2];
    const float* Wm    = (const float*)d_in[3];
    const float* bm    = (const float*)d_in[4];
    const float* alpha = (const float*)d_in[5];
    const float* beta  = (const float*)d_in[6];
    float* out = (float*)d_out;

    float* Y    = (float*)d_ws;                   // 67108864
    float* CB   = Y + 67108864;                   // 1048576
    float* NCB  = CB + 1048576;                   // 524288
    float* MAXV = NCB + 524288;                   // 1048576
    int*   MAXI = (int*)(MAXV + 1048576);         // 1048576
    float* AGG  = (float*)(MAXI + 1048576);       // 524288

    hipLaunchKernelGGL(kY,   dim3(4096), dim3(512), 0, stream, x, Wp, bp, Y);
    hipLaunchKernelGGL(kCen, dim3(256),  dim3(256), 0, stream, Y, CB);
    hipLaunchKernelGGL(kNC,  dim3(256),  dim3(64),  0, stream, CB, NCB);
    hipLaunchKernelGGL(kSim, dim3(1024), dim3(256), 0, stream, Y, NCB, alpha, beta, MAXV, MAXI);
    hipLaunchKernelGGL(kAgg, dim3(256),  dim3(256), 0, stream, Y, CB, MAXV, MAXI, AGG);
    hipLaunchKernelGGL(kOut, dim3(2048), dim3(256), 0, stream, AGG, MAXV, MAXI, Wm, bm, out);
}